// Round 1
// baseline (784.009 us; speedup 1.0000x reference)
//
#include <hip/hip_runtime.h>
#include <hip/hip_bf16.h>

// Problem constants
#define TOK 4096   // B*T
#define DD  1024   // D
#define HH  4096   // H
#define OO  1024   // O
#define EE  8      // experts
#define MAX_SLOTS 80   // max 128-row tiles across all experts (<= 64+8)

typedef float  f32x4  __attribute__((ext_vector_type(4)));
typedef __bf16 bf16x8 __attribute__((ext_vector_type(8)));
typedef __bf16 bf16x4 __attribute__((ext_vector_type(4)));
typedef unsigned int u32x4 __attribute__((ext_vector_type(4)));

union ABCast { u32x4 u; bf16x8 b; };

// ---------------- Router: fp32, one wave per token ----------------
__global__ void router_kernel(const float* __restrict__ x, const float* __restrict__ noise,
                              const float* __restrict__ Wg, const float* __restrict__ bg,
                              const float* __restrict__ Wn, const float* __restrict__ bn,
                              int* __restrict__ topk_e, float* __restrict__ topk_g,
                              int* __restrict__ cnt)
{
    int wave = threadIdx.x >> 6;
    int lane = threadIdx.x & 63;
    int token = blockIdx.x * 4 + wave;
    const float* xr = x + (size_t)token * DD;
    float accg[EE], accn[EE];
#pragma unroll
    for (int e = 0; e < EE; ++e) { accg[e] = 0.f; accn[e] = 0.f; }
    for (int jj = 0; jj < DD / 64; ++jj) {
        int d = lane + jj * 64;
        float xv = xr[d];
        const float* wgr = Wg + d * EE;
        const float* wnr = Wn + d * EE;
#pragma unroll
        for (int e = 0; e < EE; ++e) {
            accg[e] += xv * wgr[e];
            accn[e] += xv * wnr[e];
        }
    }
#pragma unroll
    for (int off = 32; off; off >>= 1) {
#pragma unroll
        for (int e = 0; e < EE; ++e) {
            accg[e] += __shfl_down(accg[e], off, 64);
            accn[e] += __shfl_down(accn[e], off, 64);
        }
    }
    if (lane == 0) {
        float noisy[EE];
#pragma unroll
        for (int e = 0; e < EE; ++e) {
            float lg = accg[e] + bg[e];
            float nl = accn[e] + bn[e];
            // stable softplus = max(z,0) + log1p(exp(-|z|))
            float sp = fmaxf(nl, 0.f) + log1pf(expf(-fabsf(nl)));
            noisy[e] = lg + noise[(size_t)token * EE + e] * sp;
        }
        int i1 = 0; float v1 = noisy[0];
#pragma unroll
        for (int e = 1; e < EE; ++e) if (noisy[e] > v1) { v1 = noisy[e]; i1 = e; }
        int i2 = -1; float v2 = -1e30f;
#pragma unroll
        for (int e = 0; e < EE; ++e) if (e != i1 && noisy[e] > v2) { v2 = noisy[e]; i2 = e; }
        float ex = expf(v2 - v1);
        float g1 = 1.f / (1.f + ex);
        float g2 = ex / (1.f + ex);
        topk_e[token * 2] = i1;  topk_e[token * 2 + 1] = i2;
        topk_g[token * 2] = g1;  topk_g[token * 2 + 1] = g2;
        atomicAdd(&cnt[i1], 1);
        atomicAdd(&cnt[i2], 1);
    }
}

// ---------------- Plan: serial scan over 8 experts ----------------
__global__ void plan_kernel(const int* __restrict__ cnt, int* __restrict__ base_row,
                            int* __restrict__ slot_e, int* __restrict__ slot_m,
                            int* __restrict__ fill)
{
    if (threadIdx.x == 0 && blockIdx.x == 0) {
        int s = 0;
        for (int e = 0; e < EE; ++e) {
            base_row[e] = s * 128;
            int tiles = (cnt[e] + 127) >> 7;
            for (int t = 0; t < tiles; ++t) { slot_e[s] = e; slot_m[s] = t; ++s; }
            fill[e] = 0;
        }
        for (int s2 = s; s2 < MAX_SLOTS; ++s2) { slot_e[s2] = -1; slot_m[s2] = 0; }
    }
}

// ---------------- Scatter: assignment -> compacted row ----------------
__global__ void scatter_kernel(const int* __restrict__ topk_e, const float* __restrict__ topk_g,
                               const int* __restrict__ base_row, int* __restrict__ fill,
                               int* __restrict__ row_token, float* __restrict__ row_gate)
{
    int t = blockIdx.x * blockDim.x + threadIdx.x;
    if (t >= TOK * 2) return;
    int e = topk_e[t];
    int pos = atomicAdd(&fill[e], 1);
    int row = base_row[e] + pos;
    row_token[row] = t >> 1;
    row_gate[row] = topk_g[t];
}

// ---------------- x fp32 -> bf16 ----------------
__global__ void convert_x_kernel(const float* __restrict__ in, __bf16* __restrict__ out)
{
    int i = blockIdx.x * blockDim.x + threadIdx.x;   // one float4 per thread
    f32x4 v = ((const f32x4*)in)[i];
    bf16x4 o;
    o.x = (__bf16)v.x; o.y = (__bf16)v.y; o.z = (__bf16)v.z; o.w = (__bf16)v.w;
    ((bf16x4*)out)[i] = o;
}

// ---------------- per-expert transpose + convert: in [R][C] f32 -> out [C][R] bf16 ----------------
__global__ void transpose_cvt_kernel(const float* __restrict__ in, __bf16* __restrict__ out,
                                     int R, int C)
{
    __shared__ __bf16 tile[32][33];
    int e = blockIdx.z;
    const float* ine = in + (size_t)e * R * C;
    __bf16* oute = out + (size_t)e * R * C;
    int tx = threadIdx.x & 31, ty = threadIdx.x >> 5;  // ty 0..7
    int c0 = blockIdx.x * 32, r0 = blockIdx.y * 32;
#pragma unroll
    for (int i = 0; i < 4; ++i) {
        int r = r0 + ty + i * 8;
        tile[ty + i * 8][tx] = (__bf16)ine[(size_t)r * C + c0 + tx];
    }
    __syncthreads();
#pragma unroll
    for (int i = 0; i < 4; ++i) {
        int c = c0 + ty + i * 8;
        oute[(size_t)c * R + r0 + tx] = tile[tx][ty + i * 8];
    }
}

// ---------------- GEMM1: h = relu(x_gathered @ W1[e] + b1[e]) ----------------
// A: gathered rows of x_bf16 [TOK][D]; B: W1t [E][H][D] (n-major); out h [MAX_SLOTS*128][H] bf16
__global__ void gemm1_kernel(const __bf16* __restrict__ xb,
                             const __bf16* __restrict__ W1t,
                             const float* __restrict__ b1bias,
                             const int* __restrict__ slot_e, const int* __restrict__ slot_m,
                             const int* __restrict__ base_row, const int* __restrict__ cnt,
                             const int* __restrict__ row_token,
                             __bf16* __restrict__ h)
{
    int slot = blockIdx.y;
    int e = slot_e[slot];
    if (e < 0) return;
    int mt = slot_m[slot];
    int row0 = base_row[e] + mt * 128;
    int rows_in = min(128, cnt[e] - mt * 128);
    int n0 = blockIdx.x * 128;

    __shared__ u32x4 Alds[4 * 128];
    __shared__ u32x4 Blds[4 * 128];

    int tid = threadIdx.x;
    int rs = tid >> 2;          // 0..63
    int kc = tid & 3;           // k-chunk of 8 bf16
    int rA0 = rs, rA1 = rs + 64;
    int tok0 = (rA0 < rows_in) ? row_token[row0 + rA0] : 0;
    int tok1 = (rA1 < rows_in) ? row_token[row0 + rA1] : 0;
    const __bf16* aptr0 = xb + (size_t)tok0 * DD + kc * 8;
    const __bf16* aptr1 = xb + (size_t)tok1 * DD + kc * 8;
    const __bf16* bbase = W1t + (size_t)e * HH * DD + (size_t)n0 * DD + kc * 8;
    const __bf16* bptr0 = bbase + (size_t)rA0 * DD;
    const __bf16* bptr1 = bbase + (size_t)rA1 * DD;

    int wave = tid >> 6, lane = tid & 63;
    int wm = wave & 1, wn = wave >> 1;
    int quad = lane >> 4, l16 = lane & 15;

    f32x4 acc[4][4];
#pragma unroll
    for (int i = 0; i < 4; ++i)
#pragma unroll
        for (int j = 0; j < 4; ++j) acc[i][j] = (f32x4)(0.0f);

    for (int k0 = 0; k0 < DD; k0 += 32) {
        u32x4 a0 = *(const u32x4*)(aptr0 + k0);
        u32x4 a1 = *(const u32x4*)(aptr1 + k0);
        u32x4 bld0 = *(const u32x4*)(bptr0 + k0);
        u32x4 bld1 = *(const u32x4*)(bptr1 + k0);
        __syncthreads();
        Alds[kc * 128 + rA0] = a0;
        Alds[kc * 128 + rA1] = a1;
        Blds[kc * 128 + rA0] = bld0;
        Blds[kc * 128 + rA1] = bld1;
        __syncthreads();
        ABCast af[4], bfr[4];
#pragma unroll
        for (int mf = 0; mf < 4; ++mf) af[mf].u = Alds[quad * 128 + wm * 64 + mf * 16 + l16];
#pragma unroll
        for (int nf = 0; nf < 4; ++nf) bfr[nf].u = Blds[quad * 128 + wn * 64 + nf * 16 + l16];
#pragma unroll
        for (int mf = 0; mf < 4; ++mf)
#pragma unroll
            for (int nf = 0; nf < 4; ++nf)
                acc[mf][nf] = __builtin_amdgcn_mfma_f32_16x16x32_bf16(af[mf].b, bfr[nf].b, acc[mf][nf], 0, 0, 0);
    }

#pragma unroll
    for (int mf = 0; mf < 4; ++mf) {
        int rl = wm * 64 + mf * 16 + quad * 4;
#pragma unroll
        for (int i = 0; i < 4; ++i) {
            int rli = rl + i;
            if (rli < rows_in) {
                size_t hrow = (size_t)(row0 + rli) * HH;
#pragma unroll
                for (int nf = 0; nf < 4; ++nf) {
                    int col = n0 + wn * 64 + nf * 16 + l16;
                    float v = acc[mf][nf][i] + b1bias[e * HH + col];
                    v = fmaxf(v, 0.f);
                    h[hrow + col] = (__bf16)v;
                }
            }
        }
    }
}

// ---------------- GEMM2: out[token] += gate * (h @ W2[e] + b2[e]) ----------------
__global__ void gemm2_kernel(const __bf16* __restrict__ h,
                             const __bf16* __restrict__ W2t,   // [E][O][H]
                             const float* __restrict__ b2bias,
                             const int* __restrict__ slot_e, const int* __restrict__ slot_m,
                             const int* __restrict__ base_row, const int* __restrict__ cnt,
                             const int* __restrict__ row_token, const float* __restrict__ row_gate,
                             float* __restrict__ out)
{
    int slot = blockIdx.y;
    int e = slot_e[slot];
    if (e < 0) return;
    int mt = slot_m[slot];
    int row0 = base_row[e] + mt * 128;
    int rows_in = min(128, cnt[e] - mt * 128);
    int n0 = blockIdx.x * 128;

    __shared__ u32x4 Alds[4 * 128];
    __shared__ u32x4 Blds[4 * 128];

    int tid = threadIdx.x;
    int rs = tid >> 2;
    int kc = tid & 3;
    int rA0 = rs, rA1 = rs + 64;
    const __bf16* abase = h + (size_t)row0 * HH + kc * 8;
    const __bf16* aptr0 = abase + (size_t)rA0 * HH;
    const __bf16* aptr1 = abase + (size_t)rA1 * HH;
    const __bf16* bbase = W2t + (size_t)e * OO * HH + (size_t)n0 * HH + kc * 8;
    const __bf16* bptr0 = bbase + (size_t)rA0 * HH;
    const __bf16* bptr1 = bbase + (size_t)rA1 * HH;

    int wave = tid >> 6, lane = tid & 63;
    int wm = wave & 1, wn = wave >> 1;
    int quad = lane >> 4, l16 = lane & 15;

    f32x4 acc[4][4];
#pragma unroll
    for (int i = 0; i < 4; ++i)
#pragma unroll
        for (int j = 0; j < 4; ++j) acc[i][j] = (f32x4)(0.0f);

    for (int k0 = 0; k0 < HH; k0 += 32) {
        u32x4 a0 = *(const u32x4*)(aptr0 + k0);
        u32x4 a1 = *(const u32x4*)(aptr1 + k0);
        u32x4 bld0 = *(const u32x4*)(bptr0 + k0);
        u32x4 bld1 = *(const u32x4*)(bptr1 + k0);
        __syncthreads();
        Alds[kc * 128 + rA0] = a0;
        Alds[kc * 128 + rA1] = a1;
        Blds[kc * 128 + rA0] = bld0;
        Blds[kc * 128 + rA1] = bld1;
        __syncthreads();
        ABCast af[4], bfr[4];
#pragma unroll
        for (int mf = 0; mf < 4; ++mf) af[mf].u = Alds[quad * 128 + wm * 64 + mf * 16 + l16];
#pragma unroll
        for (int nf = 0; nf < 4; ++nf) bfr[nf].u = Blds[quad * 128 + wn * 64 + nf * 16 + l16];
#pragma unroll
        for (int mf = 0; mf < 4; ++mf)
#pragma unroll
            for (int nf = 0; nf < 4; ++nf)
                acc[mf][nf] = __builtin_amdgcn_mfma_f32_16x16x32_bf16(af[mf].b, bfr[nf].b, acc[mf][nf], 0, 0, 0);
    }

#pragma unroll
    for (int mf = 0; mf < 4; ++mf) {
        int rl = wm * 64 + mf * 16 + quad * 4;
#pragma unroll
        for (int i = 0; i < 4; ++i) {
            int rli = rl + i;
            if (rli < rows_in) {
                int token = row_token[row0 + rli];
                float gate = row_gate[row0 + rli];
                float* orow = out + (size_t)token * OO;
#pragma unroll
                for (int nf = 0; nf < 4; ++nf) {
                    int col = n0 + wn * 64 + nf * 16 + l16;
                    float v = acc[mf][nf][i] + b2bias[e * OO + col];
                    atomicAdd(&orow[col], gate * v);
                }
            }
        }
    }
}

extern "C" void kernel_launch(void* const* d_in, const int* in_sizes, int n_in,
                              void* d_out, int out_size, void* d_ws, size_t ws_size,
                              hipStream_t stream)
{
    const float* x     = (const float*)d_in[0];
    const float* noise = (const float*)d_in[1];
    const float* Wg    = (const float*)d_in[2];
    const float* bg    = (const float*)d_in[3];
    const float* Wn    = (const float*)d_in[4];
    const float* bn    = (const float*)d_in[5];
    const float* W1    = (const float*)d_in[6];
    const float* b1    = (const float*)d_in[7];
    const float* W2    = (const float*)d_in[8];
    const float* b2    = (const float*)d_in[9];
    float* out = (float*)d_out;

    // Workspace carve-up (~217 MB total)
    char* p = (char*)d_ws;
    auto alloc = [&](size_t bytes) { char* r = p; p += (bytes + 255) & ~(size_t)255; return r; };
    __bf16* xb   = (__bf16*)alloc((size_t)TOK * DD * 2);               // 8 MB
    __bf16* W1t  = (__bf16*)alloc((size_t)EE * DD * HH * 2);           // 64 MB  [E][H][D]
    __bf16* W2t  = (__bf16*)alloc((size_t)EE * HH * OO * 2);           // 64 MB  [E][O][H]
    __bf16* hbuf = (__bf16*)alloc((size_t)MAX_SLOTS * 128 * HH * 2);   // 80 MB
    int*   topk_e    = (int*)alloc((size_t)TOK * 2 * 4);
    float* topk_g    = (float*)alloc((size_t)TOK * 2 * 4);
    int*   row_token = (int*)alloc((size_t)MAX_SLOTS * 128 * 4);
    float* row_gate  = (float*)alloc((size_t)MAX_SLOTS * 128 * 4);
    int*   cnt       = (int*)alloc(EE * 4);
    int*   fill      = (int*)alloc(EE * 4);
    int*   base_row  = (int*)alloc(EE * 4);
    int*   slot_e    = (int*)alloc(MAX_SLOTS * 4);
    int*   slot_m    = (int*)alloc(MAX_SLOTS * 4);

    hipMemsetAsync(out, 0, (size_t)out_size * 4, stream);
    hipMemsetAsync(cnt, 0, EE * 4, stream);

    router_kernel<<<TOK / 4, 256, 0, stream>>>(x, noise, Wg, bg, Wn, bn, topk_e, topk_g, cnt);
    plan_kernel<<<1, 64, 0, stream>>>(cnt, base_row, slot_e, slot_m, fill);
    scatter_kernel<<<(TOK * 2) / 256, 256, 0, stream>>>(topk_e, topk_g, base_row, fill, row_token, row_gate);
    convert_x_kernel<<<(TOK * DD / 4) / 256, 256, 0, stream>>>(x, xb);
    transpose_cvt_kernel<<<dim3(HH / 32, DD / 32, EE), 256, 0, stream>>>(W1, W1t, DD, HH);
    transpose_cvt_kernel<<<dim3(OO / 32, HH / 32, EE), 256, 0, stream>>>(W2, W2t, HH, OO);
    gemm1_kernel<<<dim3(HH / 128, MAX_SLOTS), 256, 0, stream>>>(xb, W1t, b1, slot_e, slot_m,
                                                                base_row, cnt, row_token, hbuf);
    gemm2_kernel<<<dim3(OO / 128, MAX_SLOTS), 256, 0, stream>>>(hbuf, W2t, b2, slot_e, slot_m,
                                                                base_row, cnt, row_token, row_gate, out);
}